// Round 18
// baseline (278.509 us; speedup 1.0000x reference)
//
#include <hip/hip_runtime.h>
#include <hip/hip_bf16.h>
#include <hip/hip_fp8.h>

#define NN 100000
#define NE 1600000
#define FF 128
#define HH 128
#define CC 10
#define GG 64

#define NCHUNK 2048
#define CE 782            // ceil(NE/NCHUNK)
#define NBUCKET 128
#define BSPAN 782         // ceil(NN/NBUCKET)
#define SRCBITS 17        // NN < 131072

typedef __attribute__((ext_vector_type(8))) short short8;
typedef __attribute__((ext_vector_type(4))) float f32x4;
typedef __attribute__((ext_vector_type(2))) float f32x2;

__device__ inline unsigned short f2bf(float f) {
    union { float f; unsigned int i; } x;
    x.f = f;
    unsigned int r = x.i + 0x7FFF + ((x.i >> 16) & 1);  // RNE
    return (unsigned short)(r >> 16);
}
__device__ inline unsigned char f8enc_sw(float v) {
    __hip_fp8_e4m3 q(v);
    return (unsigned char)q.__x;
}
__device__ inline float f8dec(unsigned char b) {
    __hip_fp8_e4m3 q;
    q.__x = (__hip_fp8_storage_t)b;
    return (float)q;
}

#if defined(__has_builtin)
#if __has_builtin(__builtin_amdgcn_cvt_pk_f32_fp8)
#define HAVE_CVT_PK_F32_FP8 1
#endif
#if __has_builtin(__builtin_amdgcn_cvt_pk_fp8_f32)
#define HAVE_CVT_PK_FP8 1
#endif
#endif

// decode 8 fp8 (uint2) -> 8 f32 (scalar out)
__device__ inline void dec8(uint2 v, float* o) {
#ifdef HAVE_CVT_PK_F32_FP8
    f32x2 p;
    p = __builtin_amdgcn_cvt_pk_f32_fp8(v.x, false); o[0] = p[0]; o[1] = p[1];
    p = __builtin_amdgcn_cvt_pk_f32_fp8(v.x, true);  o[2] = p[0]; o[3] = p[1];
    p = __builtin_amdgcn_cvt_pk_f32_fp8(v.y, false); o[4] = p[0]; o[5] = p[1];
    p = __builtin_amdgcn_cvt_pk_f32_fp8(v.y, true);  o[6] = p[0]; o[7] = p[1];
#else
#pragma unroll
    for (int j = 0; j < 4; ++j) {
        o[j]     = f8dec((v.x >> (8 * j)) & 0xFF);
        o[j + 4] = f8dec((v.y >> (8 * j)) & 0xFF);
    }
#endif
}
// decode 8 fp8 -> 4 packed f32x2 (enables v_pk_add_f32 accumulate)
__device__ inline void dec8p(uint2 v, f32x2* o) {
#ifdef HAVE_CVT_PK_F32_FP8
    o[0] = __builtin_amdgcn_cvt_pk_f32_fp8(v.x, false);
    o[1] = __builtin_amdgcn_cvt_pk_f32_fp8(v.x, true);
    o[2] = __builtin_amdgcn_cvt_pk_f32_fp8(v.y, false);
    o[3] = __builtin_amdgcn_cvt_pk_f32_fp8(v.y, true);
#else
    float d[8]; dec8(v, d);
#pragma unroll
    for (int j = 0; j < 4; ++j) { o[j][0] = d[2 * j]; o[j][1] = d[2 * j + 1]; }
#endif
}
// encode 4 f32 -> packed fp8 dword (HW v_cvt_pk_fp8_f32 when available)
__device__ inline unsigned enc_pk4(float a, float b, float c, float d) {
#ifdef HAVE_CVT_PK_FP8
    int w = __builtin_amdgcn_cvt_pk_fp8_f32(a, b, 0, false);
    w = __builtin_amdgcn_cvt_pk_fp8_f32(c, d, w, true);
    return (unsigned)w;
#else
    return (unsigned)f8enc_sw(a) | ((unsigned)f8enc_sw(b) << 8) |
           ((unsigned)f8enc_sw(c) << 16) | ((unsigned)f8enc_sw(d) << 24);
#endif
}
__device__ inline unsigned char f8enc1(float v) {
#ifdef HAVE_CVT_PK_FP8
    return (unsigned char)(__builtin_amdgcn_cvt_pk_fp8_f32(v, v, 0, false) & 0xFF);
#else
    return f8enc_sw(v);
#endif
}
__device__ inline unsigned pack2bf(float a, float b) {
    return (unsigned)f2bf(a) | ((unsigned)f2bf(b) << 16);
}

// -------- weight combine + pack into MFMA B-fragment order (weights only) --------
__global__ __launch_bounds__(256) void combw_kernel(const float* __restrict__ W1, const float* __restrict__ b1,
                                                    const float* __restrict__ Wr1, const float* __restrict__ br1,
                                                    const float* __restrict__ W2, const float* __restrict__ b2,
                                                    const float* __restrict__ Wr, const float* __restrict__ br,
                                                    unsigned short* __restrict__ Wpack, float* __restrict__ bc) {
    int idx = blockIdx.x * 256 + threadIdx.x;   // < 3*16384
    if (idx >= 3 * 16384) return;
    int l = idx / 16384, rem = idx % 16384;
    int cb = rem / 2048;
    int kb = (rem / 512) % 4;
    int lane = (rem / 8) % 64;
    int j = rem % 8;
    int k = kb * 32 + (lane >> 4) * 8 + j;
    int c = cb * 16 + (lane & 15);
    int wi = k * HH + c;
    float v = (l == 0) ? 0.95f * W1[wi] + 0.05f * Wr1[wi]
                       : 0.95f * W2[(l - 1) * 16384 + wi] + 0.05f * Wr[wi];
    Wpack[idx] = f2bf(v);
    if (rem < HH) {
        bc[l * HH + rem] = (l == 0) ? 0.95f * b1[rem] + 0.05f * br1[rem]
                                    : 0.95f * b2[(l - 1) * HH + rem] + 0.05f * br[rem];
    }
}

// ---- A1: per-chunk per-bucket counts (LDS histogram, no global atomics) ----
__global__ __launch_bounds__(256) void partA1_kernel(const int* __restrict__ ei,
                                                     int* __restrict__ cc) {
    __shared__ int h[NBUCKET];
    int c = blockIdx.x, t = threadIdx.x;
    if (t < NBUCKET) h[t] = 0;
    __syncthreads();
    int beg = c * CE, end = min(beg + CE, NE);
    for (int e = beg + t; e < end; e += 256)
        atomicAdd(&h[ei[NE + e] / BSPAN], 1);
    __syncthreads();
    if (t < NBUCKET) cc[c * NBUCKET + t] = h[t];
}

// ---- A2: per-bucket exclusive scan over 2048 chunks (in-place on cc); tot[b] out ----
__global__ __launch_bounds__(256) void partA2_kernel(int* __restrict__ cc,
                                                     int* __restrict__ tot) {
    __shared__ int sh[256];
    int b = blockIdx.x, t = threadIdx.x;
    int v[8]; int s = 0;
#pragma unroll
    for (int i = 0; i < 8; ++i) { v[i] = cc[(t * 8 + i) * NBUCKET + b]; s += v[i]; }
    sh[t] = s; __syncthreads();
    for (int off = 1; off < 256; off <<= 1) {
        int x = (t >= off) ? sh[t - off] : 0; __syncthreads();
        sh[t] += x; __syncthreads();
    }
    int excl = sh[t] - s;
#pragma unroll
    for (int i = 0; i < 8; ++i) {
        cc[(t * 8 + i) * NBUCKET + b] = excl;
        excl += v[i];
    }
    if (t == 255) tot[b] = sh[255];
}

// ---- A3: scatter packed (local_dst<<17 | src) into COMPACT bucketed eb32 ----
__global__ __launch_bounds__(256) void partA3_kernel(const int* __restrict__ ei,
                                                     const int* __restrict__ cc,
                                                     const int* __restrict__ tot,
                                                     unsigned* __restrict__ eb32) {
    __shared__ int stot[NBUCKET];
    __shared__ int cur[NBUCKET];
    int c = blockIdx.x, t = threadIdx.x;
    if (t < NBUCKET) stot[t] = tot[t];
    __syncthreads();
    for (int off = 1; off < NBUCKET; off <<= 1) {
        int x = (t < NBUCKET && t >= off) ? stot[t - off] : 0;
        __syncthreads();
        if (t < NBUCKET) stot[t] += x;
        __syncthreads();
    }
    if (t < NBUCKET) cur[t] = (stot[t] - tot[t]) + cc[c * NBUCKET + t];
    __syncthreads();
    int beg = c * CE, end = min(beg + CE, NE);
    for (int e = beg + t; e < end; e += 256) {
        int d = ei[NE + e];
        int s = ei[e];
        int b = d / BSPAN;
        int ld = d - b * BSPAN;
        int p = atomicAdd(&cur[b], 1);
        eb32[p] = (unsigned)s | ((unsigned)ld << SRCBITS);
    }
}

// ---- B (fused): bucket hist -> offs + dinv -> CSR scatter (eb slice L2-hot) ----
__global__ __launch_bounds__(256) void partB_kernel(const unsigned* __restrict__ eb32,
                                                    const int* __restrict__ tot,
                                                    int* __restrict__ offs,
                                                    float* __restrict__ dinv,
                                                    int* __restrict__ csrc) {
    __shared__ int hcnt[BSPAN];
    __shared__ int lcur[BSPAN];
    __shared__ int sh[256];
    __shared__ int gbase_sh;
    int b = blockIdx.x, t = threadIdx.x;
    int lo = b * BSPAN;
    int span = min(BSPAN, NN - lo);
    if (span <= 0) return;
    for (int i = t; i < span; i += 256) hcnt[i] = 0;
    if (t == 0) {
        int g = 0;
        for (int i = 0; i < b; ++i) g += tot[i];
        gbase_sh = g;
    }
    __syncthreads();
    int gbase = gbase_sh;
    int len = tot[b];
    const unsigned* ebb = eb32 + (size_t)gbase;
    for (int e = t; e < len; e += 256)
        atomicAdd(&hcnt[ebb[e] >> SRCBITS], 1);
    __syncthreads();
    int base = t * 4;
    int v[4]; int s = 0;
#pragma unroll
    for (int j = 0; j < 4; ++j) { int i = base + j; v[j] = (i < span) ? hcnt[i] : 0; s += v[j]; }
    sh[t] = s; __syncthreads();
    for (int off = 1; off < 256; off <<= 1) {
        int x = (t >= off) ? sh[t - off] : 0; __syncthreads();
        sh[t] += x; __syncthreads();
    }
    int excl = sh[t] - s + gbase;
#pragma unroll
    for (int j = 0; j < 4; ++j) {
        int i = base + j;
        if (i < span) {
            offs[lo + i] = excl;
            lcur[i] = excl;
            dinv[lo + i] = rsqrtf((float)v[j] + 1.0f);
            excl += v[j];
        }
    }
    if (b == NBUCKET - 1 && t == 0) offs[NN] = NE;
    __syncthreads();
    for (int e = t; e < len; e += 256) {
        unsigned pr = ebb[e];
        int p = atomicAdd(&lcur[pr >> SRCBITS], 1);
        csrc[p] = (int)(pr & ((1u << SRCBITS) - 1));
    }
}

// ------- MFMA GEMM layer 0: reads f32 x directly (bf16 fragments in-register) -------
__global__ __launch_bounds__(256) void gemm_f32_kernel(const float* __restrict__ A,
                                                       const unsigned short* __restrict__ Wp,
                                                       const float* __restrict__ dinv,
                                                       unsigned char* __restrict__ out8,
                                                       int nrows) {
    __shared__ unsigned char f8s[64][128];
    int w = threadIdx.x >> 6;
    int l = threadIdx.x & 63;
    int m0 = blockIdx.x * 64 + w * 16;
    int kg = l >> 4;
    int cl = l & 15;
    int arow = m0 + cl;

    short8 a[4];
    if (arow < nrows) {
        const float4* Ar4 = (const float4*)(A + (size_t)arow * HH);
#pragma unroll
        for (int kb = 0; kb < 4; ++kb) {
            float4 u0 = Ar4[kb * 8 + kg * 2];
            float4 u1 = Ar4[kb * 8 + kg * 2 + 1];
            short8 tt;
            tt[0] = (short)f2bf(u0.x); tt[1] = (short)f2bf(u0.y);
            tt[2] = (short)f2bf(u0.z); tt[3] = (short)f2bf(u0.w);
            tt[4] = (short)f2bf(u1.x); tt[5] = (short)f2bf(u1.y);
            tt[6] = (short)f2bf(u1.z); tt[7] = (short)f2bf(u1.w);
            a[kb] = tt;
        }
    } else {
        short8 z = {};
#pragma unroll
        for (int kb = 0; kb < 4; ++kb) a[kb] = z;
    }

    float dv[4];
#pragma unroll
    for (int r = 0; r < 4; ++r) {
        int orow = m0 + kg * 4 + r;
        dv[r] = (orow < nrows) ? dinv[orow] : 0.f;
    }

#pragma unroll
    for (int cb = 0; cb < 8; ++cb) {
        f32x4 acc = {0.f, 0.f, 0.f, 0.f};
#pragma unroll
        for (int kb = 0; kb < 4; ++kb) {
            short8 b = *(const short8*)(Wp + (size_t)(cb * 4 + kb) * 512 + l * 8);
            acc = __builtin_amdgcn_mfma_f32_16x16x32_bf16(a[kb], b, acc, 0, 0, 0);
        }
#pragma unroll
        for (int r = 0; r < 4; ++r)
            f8s[w * 16 + kg * 4 + r][cb * 16 + cl] = f8enc1(acc[r] * dv[r]);
    }
    __syncthreads();
    int blk0 = blockIdx.x * 64;
    for (int u = threadIdx.x; u < 512; u += 256) {
        int row = u >> 3, c16 = u & 7;
        int grow = blk0 + row;
        if (grow < nrows)
            ((uint4*)out8)[(size_t)grow * 8 + c16] = ((const uint4*)&f8s[row][0])[c16];
    }
}

// ===== FUSED agg(layer l) + gemm(layer l+1): 32 nodes/block, no h8 round-trip =====
// Conflict-free LDS layout: row r's features f=16q+j stored as two 16B units at
// byte cols q*16 (j<8) and 128+q*16 (j>=8), swizzled ^((r&7)<<4).
__global__ __launch_bounds__(256) void agg_gemm_kernel(const unsigned char* __restrict__ t8in,
                                                       const int* __restrict__ offs,
                                                       const int* __restrict__ csrc,
                                                       const float* __restrict__ dinv,
                                                       const float* __restrict__ bias,
                                                       const unsigned short* __restrict__ Wp,
                                                       unsigned char* __restrict__ t8out) {
    __shared__ unsigned char hbuf[32 * 256];
    __shared__ unsigned char f8s[32][128];
    __shared__ float sdinv[32];
    int n0 = blockIdx.x * 32;
    int ln = threadIdx.x >> 3;                 // node slot 0..31
    int lane = threadIdx.x & 7;                // features lane*16..+15
    int n = n0 + ln;

    // ---- phase 1: aggregation ----
    int beg = offs[n], end = offs[n + 1];
    const uint4* g16 = (const uint4*)t8in;
    f32x2 acc2[8] = {};
    f32x2 d2[4];
    int e = beg;
    for (; e + 7 < end; e += 8) {
        uint4 v[8];
#pragma unroll
        for (int q = 0; q < 8; ++q)
            v[q] = g16[(size_t)csrc[e + q] * 8 + lane];
#pragma unroll
        for (int q = 0; q < 8; ++q) {
            uint2 a, b;
            a.x = v[q].x; a.y = v[q].y; b.x = v[q].z; b.y = v[q].w;
            dec8p(a, d2);
#pragma unroll
            for (int k = 0; k < 4; ++k) acc2[k] += d2[k];
            dec8p(b, d2);
#pragma unroll
            for (int k = 0; k < 4; ++k) acc2[k + 4] += d2[k];
        }
    }
    for (; e <= end; ++e) {                    // includes self term at e==end
        int s = (e < end) ? csrc[e] : n;
        uint4 v = g16[(size_t)s * 8 + lane];
        uint2 a, b;
        a.x = v.x; a.y = v.y; b.x = v.z; b.y = v.w;
        dec8p(a, d2);
#pragma unroll
        for (int k = 0; k < 4; ++k) acc2[k] += d2[k];
        dec8p(b, d2);
#pragma unroll
        for (int k = 0; k < 4; ++k) acc2[k + 4] += d2[k];
    }
    float dn = dinv[n];
    if (lane == 0) sdinv[ln] = dn;
    const float4* bv = (const float4*)(bias + lane * 16);
    float bb[16];
    {
        float4 b0 = bv[0], b1 = bv[1], b2 = bv[2], b3 = bv[3];
        bb[0]=b0.x; bb[1]=b0.y; bb[2]=b0.z; bb[3]=b0.w;
        bb[4]=b1.x; bb[5]=b1.y; bb[6]=b1.z; bb[7]=b1.w;
        bb[8]=b2.x; bb[9]=b2.y; bb[10]=b2.z; bb[11]=b2.w;
        bb[12]=b3.x; bb[13]=b3.y; bb[14]=b3.z; bb[15]=b3.w;
    }
    float o[16];
#pragma unroll
    for (int j = 0; j < 16; ++j)
        o[j] = fmaxf(fmaf(acc2[j >> 1][j & 1], dn, bb[j]), 0.f);
    uint4 u0, u1;
    u0.x = pack2bf(o[0], o[1]);  u0.y = pack2bf(o[2], o[3]);
    u0.z = pack2bf(o[4], o[5]);  u0.w = pack2bf(o[6], o[7]);
    u1.x = pack2bf(o[8], o[9]);  u1.y = pack2bf(o[10], o[11]);
    u1.z = pack2bf(o[12], o[13]); u1.w = pack2bf(o[14], o[15]);
    unsigned swz = (unsigned)((ln & 7) << 4);
    unsigned rowbase = (unsigned)ln * 256;
    *(uint4*)(hbuf + ((rowbase + (unsigned)lane * 16) ^ swz)) = u0;           // j<8 half
    *(uint4*)(hbuf + ((rowbase + 128u + (unsigned)lane * 16) ^ swz)) = u1;    // j>=8 half
    __syncthreads();

    // ---- phase 2: next-layer GEMM on the 32 rows ----
    int wv = threadIdx.x >> 6;
    int l = threadIdx.x & 63;
    int rt = wv & 1;
    int ch = wv >> 1;
    int kg = l >> 4;
    int cl = l & 15;
    int arow = rt * 16 + cl;
    unsigned rswz = (unsigned)((arow & 7) << 4);
    short8 a[4];
#pragma unroll
    for (int kb = 0; kb < 4; ++kb) {
        int m = kb * 4 + kg;                               // feature block 8m..8m+7
        unsigned col = (unsigned)((m & 1) * 128 + (m >> 1) * 16);
        unsigned boff = (unsigned)arow * 256 + col;
        a[kb] = *(const short8*)(hbuf + (boff ^ rswz));
    }
    float dv[4];
#pragma unroll
    for (int r = 0; r < 4; ++r) dv[r] = sdinv[rt * 16 + kg * 4 + r];
#pragma unroll
    for (int q = 0; q < 4; ++q) {
        int cb = ch * 4 + q;
        f32x4 acc = {0.f, 0.f, 0.f, 0.f};
#pragma unroll
        for (int kb = 0; kb < 4; ++kb) {
            short8 b = *(const short8*)(Wp + (size_t)(cb * 4 + kb) * 512 + l * 8);
            acc = __builtin_amdgcn_mfma_f32_16x16x32_bf16(a[kb], b, acc, 0, 0, 0);
        }
#pragma unroll
        for (int r = 0; r < 4; ++r)
            f8s[rt * 16 + kg * 4 + r][cb * 16 + cl] = f8enc1(acc[r] * dv[r]);
    }
    __syncthreads();
    int row2 = threadIdx.x >> 3, c16 = threadIdx.x & 7;
    ((uint4*)t8out)[(size_t)(n0 + row2) * 8 + c16] = ((const uint4*)&f8s[row2][0])[c16];
}

// ===== FUSED final agg + pooling: f32 h never materialized; partials -> psum =====
__global__ __launch_bounds__(256) void agg_pool_kernel(const unsigned char* __restrict__ t8,
                                                       const int* __restrict__ offs,
                                                       const int* __restrict__ csrc,
                                                       const float* __restrict__ dinv,
                                                       const float* __restrict__ bias,
                                                       const int* __restrict__ batch,
                                                       float* __restrict__ psum) {
    __shared__ float pg[2][HH];
    int n0 = blockIdx.x * 32;
    int ln = threadIdx.x >> 3;
    int lane = threadIdx.x & 7;
    int n = n0 + ln;

    pg[threadIdx.x >> 7][threadIdx.x & 127] = 0.f;   // zero 2*128 floats
    __syncthreads();

    int beg = offs[n], end = offs[n + 1];
    const uint4* g16 = (const uint4*)t8;
    f32x2 acc2[8] = {};
    f32x2 d2[4];
    int e = beg;
    for (; e + 7 < end; e += 8) {
        uint4 v[8];
#pragma unroll
        for (int q = 0; q < 8; ++q)
            v[q] = g16[(size_t)csrc[e + q] * 8 + lane];
#pragma unroll
        for (int q = 0; q < 8; ++q) {
            uint2 a, b;
            a.x = v[q].x; a.y = v[q].y; b.x = v[q].z; b.y = v[q].w;
            dec8p(a, d2);
#pragma unroll
            for (int k = 0; k < 4; ++k) acc2[k] += d2[k];
            dec8p(b, d2);
#pragma unroll
            for (int k = 0; k < 4; ++k) acc2[k + 4] += d2[k];
        }
    }
    for (; e <= end; ++e) {
        int s = (e < end) ? csrc[e] : n;
        uint4 v = g16[(size_t)s * 8 + lane];
        uint2 a, b;
        a.x = v.x; a.y = v.y; b.x = v.z; b.y = v.w;
        dec8p(a, d2);
#pragma unroll
        for (int k = 0; k < 4; ++k) acc2[k] += d2[k];
        dec8p(b, d2);
#pragma unroll
        for (int k = 0; k < 4; ++k) acc2[k + 4] += d2[k];
    }
    float dn = dinv[n];
    const float4* bv = (const float4*)(bias + lane * 16);
    float bb[16];
    {
        float4 b0 = bv[0], b1 = bv[1], b2 = bv[2], b3 = bv[3];
        bb[0]=b0.x; bb[1]=b0.y; bb[2]=b0.z; bb[3]=b0.w;
        bb[4]=b1.x; bb[5]=b1.y; bb[6]=b1.z; bb[7]=b1.w;
        bb[8]=b2.x; bb[9]=b2.y; bb[10]=b2.z; bb[11]=b2.w;
        bb[12]=b3.x; bb[13]=b3.y; bb[14]=b3.z; bb[15]=b3.w;
    }
    int g0 = batch[n0];
    int gn = batch[n];
    int slot = gn - g0;
    if (slot <= 1) {
#pragma unroll
        for (int j = 0; j < 16; ++j) {
            float v = fmaxf(fmaf(acc2[j >> 1][j & 1], dn, bb[j]), 0.f);
            atomicAdd(&pg[slot][lane * 16 + j], v);
        }
    } else {  // pathological tiny-graph fallback (never expected)
#pragma unroll
        for (int j = 0; j < 16; ++j) {
            float v = fmaxf(fmaf(acc2[j >> 1][j & 1], dn, bb[j]), 0.f);
            atomicAdd(&psum[(size_t)gn * HH + lane * 16 + j], v);
        }
    }
    __syncthreads();
    int gEnd = batch[n0 + 31];
    int t = threadIdx.x;
    if (t < HH) {
        atomicAdd(&psum[(size_t)g0 * HH + t], pg[0][t]);
    } else if (gEnd > g0) {
        atomicAdd(&psum[(size_t)(g0 + 1) * HH + (t - HH)], pg[1][t - HH]);
    }
}

// -------- MLP + log_softmax: one block per graph (reads psum directly) --------
__global__ __launch_bounds__(128) void mlp2_kernel(const float* __restrict__ psum,
                                                   const int* __restrict__ batch,
                                                   const float* __restrict__ Wl1,
                                                   const float* __restrict__ bl1,
                                                   const float* __restrict__ Wl2,
                                                   const float* __restrict__ bl2,
                                                   float* __restrict__ out) {
    __shared__ float p[128], o1[128], lg[CC];
    int g = blockIdx.x, t = threadIdx.x;
    int lo = 0, hi = NN;
    while (lo < hi) { int m = (lo + hi) >> 1; if (batch[m] < g) lo = m + 1; else hi = m; }
    int lb = lo;
    lo = 0; hi = NN;
    while (lo < hi) { int m = (lo + hi) >> 1; if (batch[m] <= g) lo = m + 1; else hi = m; }
    int len = lo - lb;
    p[t] = psum[(size_t)g * HH + t] / fmaxf((float)len, 1.f);
    __syncthreads();
    float acc = bl1[t];
    for (int k = 0; k < HH; ++k) acc = fmaf(p[k], Wl1[k * HH + t], acc);
    o1[t] = fmaxf(acc, 0.f);
    __syncthreads();
    if (t < CC) {
        float a2 = bl2[t];
        for (int j = 0; j < HH; ++j) a2 = fmaf(o1[j], Wl2[j * CC + t], a2);
        lg[t] = a2;
    }
    __syncthreads();
    if (t == 0) {
        float m = lg[0];
        for (int c = 1; c < CC; ++c) m = fmaxf(m, lg[c]);
        float s = 0.f;
        for (int c = 0; c < CC; ++c) s += expf(lg[c] - m);
        float ls = logf(s);
        for (int c = 0; c < CC; ++c) out[g * CC + c] = lg[c] - m - ls;
    }
}

extern "C" void kernel_launch(void* const* d_in, const int* in_sizes, int n_in,
                              void* d_out, int out_size, void* d_ws, size_t ws_size,
                              hipStream_t stream) {
    const float* x   = (const float*)d_in[0];
    const int*   ei  = (const int*)d_in[1];
    const int*   bat = (const int*)d_in[2];
    const float* W1  = (const float*)d_in[3];
    const float* b1  = (const float*)d_in[4];
    const float* Wr1 = (const float*)d_in[5];
    const float* br1 = (const float*)d_in[6];
    const float* W2  = (const float*)d_in[7];
    const float* b2  = (const float*)d_in[8];
    const float* Wr  = (const float*)d_in[9];
    const float* br  = (const float*)d_in[10];
    const float* Wl1 = (const float*)d_in[11];
    const float* bl1 = (const float*)d_in[12];
    const float* Wl2 = (const float*)d_in[13];
    const float* bl2 = (const float*)d_in[14];
    float* out = (float*)d_out;

    // workspace carve-up (256B aligned)
    char* base = (char*)d_ws;
    size_t off = 0;
    auto alloc = [&](size_t bytes) {
        void* p = base + off;
        off += (bytes + 255) & ~(size_t)255;
        return p;
    };
    unsigned char* t8a  = (unsigned char*)alloc((size_t)NN * HH);
    unsigned char* t8b  = (unsigned char*)alloc((size_t)NN * HH);
    unsigned* eb32 = (unsigned*)alloc((size_t)NE * 4);
    int*   cc     = (int*)alloc((size_t)NCHUNK * NBUCKET * 4);
    int*   csrc   = (int*)alloc((size_t)NE * 4);
    int*   offs   = (int*)alloc((size_t)(NN + 1) * 4);
    float* dinv   = (float*)alloc((size_t)NN * 4);
    int*   tot    = (int*)alloc(NBUCKET * 4);
    unsigned short* Wpack = (unsigned short*)alloc(3 * 16384 * 2);
    float* bc     = (float*)alloc(3 * HH * 4);
    float* psum   = (float*)alloc((size_t)GG * HH * 4);
    (void)ws_size; (void)in_sizes; (void)n_in; (void)out_size;

    hipMemsetAsync(psum, 0, (size_t)GG * HH * 4, stream);

    // weight combine
    combw_kernel<<<192, 256, 0, stream>>>(W1, b1, Wr1, br1, W2, b2, Wr, br, Wpack, bc);

    // deterministic partition: 4 kernels, no global atomics
    partA1_kernel<<<NCHUNK, 256, 0, stream>>>(ei, cc);
    partA2_kernel<<<NBUCKET, 256, 0, stream>>>(cc, tot);
    partA3_kernel<<<NCHUNK, 256, 0, stream>>>(ei, cc, tot, eb32);
    partB_kernel<<<NBUCKET, 256, 0, stream>>>(eb32, tot, offs, dinv, csrc);

    const int GEMM_BLOCKS = (NN + 63) / 64;
    const int FUSE_BLOCKS = NN / 32;   // 3125, exact
    // layer 0 GEMM (f32 x direct)
    gemm_f32_kernel<<<GEMM_BLOCKS, 256, 0, stream>>>(x, Wpack, dinv, t8a, NN);
    // fused agg(L0)+gemm(L1): t8a -> t8b
    agg_gemm_kernel<<<FUSE_BLOCKS, 256, 0, stream>>>(t8a, offs, csrc, dinv, bc,
                                                     Wpack + 16384, t8b);
    // fused agg(L1)+gemm(L2): t8b -> t8a
    agg_gemm_kernel<<<FUSE_BLOCKS, 256, 0, stream>>>(t8b, offs, csrc, dinv, bc + HH,
                                                     Wpack + 2 * 16384, t8a);
    // fused final agg + pooling (f32 partials straight into psum)
    agg_pool_kernel<<<FUSE_BLOCKS, 256, 0, stream>>>(t8a, offs, csrc, dinv, bc + 2 * HH,
                                                     bat, psum);

    // readout
    mlp2_kernel<<<GG, 128, 0, stream>>>(psum, bat, Wl1, bl1, Wl2, bl2, out);
}

// Round 19
// 225.903 us; speedup vs baseline: 1.2329x; 1.2329x over previous
//
#include <hip/hip_runtime.h>
#include <hip/hip_bf16.h>
#include <hip/hip_fp8.h>

#define NN 100000
#define NE 1600000
#define FF 128
#define HH 128
#define CC 10
#define GG 64

#define NCHUNK 2048
#define CE 782            // ceil(NE/NCHUNK)
#define NBUCKET 128
#define BSPAN 782         // ceil(NN/NBUCKET)
#define PSEG 16
#define SRCBITS 17        // NN < 131072

typedef __attribute__((ext_vector_type(8))) short short8;
typedef __attribute__((ext_vector_type(4))) float f32x4;
typedef __attribute__((ext_vector_type(2))) float f32x2;

__device__ inline unsigned short f2bf(float f) {
    union { float f; unsigned int i; } x;
    x.f = f;
    unsigned int r = x.i + 0x7FFF + ((x.i >> 16) & 1);  // RNE
    return (unsigned short)(r >> 16);
}
__device__ inline unsigned char f8enc_sw(float v) {
    __hip_fp8_e4m3 q(v);
    return (unsigned char)q.__x;
}
__device__ inline float f8dec(unsigned char b) {
    __hip_fp8_e4m3 q;
    q.__x = (__hip_fp8_storage_t)b;
    return (float)q;
}

#if defined(__has_builtin)
#if __has_builtin(__builtin_amdgcn_cvt_pk_f32_fp8)
#define HAVE_CVT_PK_F32_FP8 1
#endif
#if __has_builtin(__builtin_amdgcn_cvt_pk_fp8_f32)
#define HAVE_CVT_PK_FP8 1
#endif
#endif

// decode 8 fp8 (uint2) -> 8 f32 (scalar out)
__device__ inline void dec8(uint2 v, float* o) {
#ifdef HAVE_CVT_PK_F32_FP8
    f32x2 p;
    p = __builtin_amdgcn_cvt_pk_f32_fp8(v.x, false); o[0] = p[0]; o[1] = p[1];
    p = __builtin_amdgcn_cvt_pk_f32_fp8(v.x, true);  o[2] = p[0]; o[3] = p[1];
    p = __builtin_amdgcn_cvt_pk_f32_fp8(v.y, false); o[4] = p[0]; o[5] = p[1];
    p = __builtin_amdgcn_cvt_pk_f32_fp8(v.y, true);  o[6] = p[0]; o[7] = p[1];
#else
#pragma unroll
    for (int j = 0; j < 4; ++j) {
        o[j]     = f8dec((v.x >> (8 * j)) & 0xFF);
        o[j + 4] = f8dec((v.y >> (8 * j)) & 0xFF);
    }
#endif
}
// decode 8 fp8 -> 4 packed f32x2 (enables v_pk_add_f32 accumulate)
__device__ inline void dec8p(uint2 v, f32x2* o) {
#ifdef HAVE_CVT_PK_F32_FP8
    o[0] = __builtin_amdgcn_cvt_pk_f32_fp8(v.x, false);
    o[1] = __builtin_amdgcn_cvt_pk_f32_fp8(v.x, true);
    o[2] = __builtin_amdgcn_cvt_pk_f32_fp8(v.y, false);
    o[3] = __builtin_amdgcn_cvt_pk_f32_fp8(v.y, true);
#else
    float d[8]; dec8(v, d);
#pragma unroll
    for (int j = 0; j < 4; ++j) { o[j][0] = d[2 * j]; o[j][1] = d[2 * j + 1]; }
#endif
}
// encode 4 f32 -> packed fp8 dword (HW v_cvt_pk_fp8_f32 when available)
__device__ inline unsigned enc_pk4(float a, float b, float c, float d) {
#ifdef HAVE_CVT_PK_FP8
    int w = __builtin_amdgcn_cvt_pk_fp8_f32(a, b, 0, false);
    w = __builtin_amdgcn_cvt_pk_fp8_f32(c, d, w, true);
    return (unsigned)w;
#else
    return (unsigned)f8enc_sw(a) | ((unsigned)f8enc_sw(b) << 8) |
           ((unsigned)f8enc_sw(c) << 16) | ((unsigned)f8enc_sw(d) << 24);
#endif
}
__device__ inline unsigned char f8enc1(float v) {
#ifdef HAVE_CVT_PK_FP8
    return (unsigned char)(__builtin_amdgcn_cvt_pk_fp8_f32(v, v, 0, false) & 0xFF);
#else
    return f8enc_sw(v);
#endif
}
__device__ inline unsigned pack2bf(float a, float b) {
    return (unsigned)f2bf(a) | ((unsigned)f2bf(b) << 16);
}

// -------- weight combine + pack into MFMA B-fragment order (weights only) --------
__global__ __launch_bounds__(256) void combw_kernel(const float* __restrict__ W1, const float* __restrict__ b1,
                                                    const float* __restrict__ Wr1, const float* __restrict__ br1,
                                                    const float* __restrict__ W2, const float* __restrict__ b2,
                                                    const float* __restrict__ Wr, const float* __restrict__ br,
                                                    unsigned short* __restrict__ Wpack, float* __restrict__ bc) {
    int idx = blockIdx.x * 256 + threadIdx.x;   // < 3*16384
    if (idx >= 3 * 16384) return;
    int l = idx / 16384, rem = idx % 16384;
    int cb = rem / 2048;
    int kb = (rem / 512) % 4;
    int lane = (rem / 8) % 64;
    int j = rem % 8;
    int k = kb * 32 + (lane >> 4) * 8 + j;
    int c = cb * 16 + (lane & 15);
    int wi = k * HH + c;
    float v = (l == 0) ? 0.95f * W1[wi] + 0.05f * Wr1[wi]
                       : 0.95f * W2[(l - 1) * 16384 + wi] + 0.05f * Wr[wi];
    Wpack[idx] = f2bf(v);
    if (rem < HH) {
        bc[l * HH + rem] = (l == 0) ? 0.95f * b1[rem] + 0.05f * br1[rem]
                                    : 0.95f * b2[(l - 1) * HH + rem] + 0.05f * br[rem];
    }
}

// ---- A1: per-chunk per-bucket counts (LDS histogram, no global atomics) ----
__global__ __launch_bounds__(256) void partA1_kernel(const int* __restrict__ ei,
                                                     int* __restrict__ cc) {
    __shared__ int h[NBUCKET];
    int c = blockIdx.x, t = threadIdx.x;
    if (t < NBUCKET) h[t] = 0;
    __syncthreads();
    int beg = c * CE, end = min(beg + CE, NE);
    for (int e = beg + t; e < end; e += 256)
        atomicAdd(&h[ei[NE + e] / BSPAN], 1);
    __syncthreads();
    if (t < NBUCKET) cc[c * NBUCKET + t] = h[t];
}

// ---- A2: per-bucket exclusive scan over 2048 chunks (in-place on cc); tot[b] out ----
__global__ __launch_bounds__(256) void partA2_kernel(int* __restrict__ cc,
                                                     int* __restrict__ tot) {
    __shared__ int sh[256];
    int b = blockIdx.x, t = threadIdx.x;
    int v[8]; int s = 0;
#pragma unroll
    for (int i = 0; i < 8; ++i) { v[i] = cc[(t * 8 + i) * NBUCKET + b]; s += v[i]; }
    sh[t] = s; __syncthreads();
    for (int off = 1; off < 256; off <<= 1) {
        int x = (t >= off) ? sh[t - off] : 0; __syncthreads();
        sh[t] += x; __syncthreads();
    }
    int excl = sh[t] - s;
#pragma unroll
    for (int i = 0; i < 8; ++i) {
        cc[(t * 8 + i) * NBUCKET + b] = excl;
        excl += v[i];
    }
    if (t == 255) tot[b] = sh[255];
}

// ---- A3: scatter packed (local_dst<<17 | src) into COMPACT bucketed eb32 ----
__global__ __launch_bounds__(256) void partA3_kernel(const int* __restrict__ ei,
                                                     const int* __restrict__ cc,
                                                     const int* __restrict__ tot,
                                                     unsigned* __restrict__ eb32) {
    __shared__ int stot[NBUCKET];
    __shared__ int cur[NBUCKET];
    int c = blockIdx.x, t = threadIdx.x;
    if (t < NBUCKET) stot[t] = tot[t];
    __syncthreads();
    for (int off = 1; off < NBUCKET; off <<= 1) {
        int x = (t < NBUCKET && t >= off) ? stot[t - off] : 0;
        __syncthreads();
        if (t < NBUCKET) stot[t] += x;
        __syncthreads();
    }
    if (t < NBUCKET) cur[t] = (stot[t] - tot[t]) + cc[c * NBUCKET + t];
    __syncthreads();
    int beg = c * CE, end = min(beg + CE, NE);
    for (int e = beg + t; e < end; e += 256) {
        int d = ei[NE + e];
        int s = ei[e];
        int b = d / BSPAN;
        int ld = d - b * BSPAN;
        int p = atomicAdd(&cur[b], 1);
        eb32[p] = (unsigned)s | ((unsigned)ld << SRCBITS);
    }
}

// ---- B (fused): bucket hist -> offs + dinv -> CSR scatter (eb slice L2-hot) ----
__global__ __launch_bounds__(256) void partB_kernel(const unsigned* __restrict__ eb32,
                                                    const int* __restrict__ tot,
                                                    int* __restrict__ offs,
                                                    float* __restrict__ dinv,
                                                    int* __restrict__ csrc) {
    __shared__ int hcnt[BSPAN];
    __shared__ int lcur[BSPAN];
    __shared__ int sh[256];
    __shared__ int gbase_sh;
    int b = blockIdx.x, t = threadIdx.x;
    int lo = b * BSPAN;
    int span = min(BSPAN, NN - lo);
    if (span <= 0) return;
    for (int i = t; i < span; i += 256) hcnt[i] = 0;
    if (t == 0) {
        int g = 0;
        for (int i = 0; i < b; ++i) g += tot[i];
        gbase_sh = g;
    }
    __syncthreads();
    int gbase = gbase_sh;
    int len = tot[b];
    const unsigned* ebb = eb32 + (size_t)gbase;
    for (int e = t; e < len; e += 256)
        atomicAdd(&hcnt[ebb[e] >> SRCBITS], 1);
    __syncthreads();
    int base = t * 4;
    int v[4]; int s = 0;
#pragma unroll
    for (int j = 0; j < 4; ++j) { int i = base + j; v[j] = (i < span) ? hcnt[i] : 0; s += v[j]; }
    sh[t] = s; __syncthreads();
    for (int off = 1; off < 256; off <<= 1) {
        int x = (t >= off) ? sh[t - off] : 0; __syncthreads();
        sh[t] += x; __syncthreads();
    }
    int excl = sh[t] - s + gbase;
#pragma unroll
    for (int j = 0; j < 4; ++j) {
        int i = base + j;
        if (i < span) {
            offs[lo + i] = excl;
            lcur[i] = excl;
            dinv[lo + i] = rsqrtf((float)v[j] + 1.0f);
            excl += v[j];
        }
    }
    if (b == NBUCKET - 1 && t == 0) offs[NN] = NE;
    __syncthreads();
    for (int e = t; e < len; e += 256) {
        unsigned pr = ebb[e];
        int p = atomicAdd(&lcur[pr >> SRCBITS], 1);
        csrc[p] = (int)(pr & ((1u << SRCBITS) - 1));
    }
}

// ------- MFMA GEMM layer 0: reads f32 x directly (bf16 fragments in-register) -------
__global__ __launch_bounds__(256) void gemm_f32_kernel(const float* __restrict__ A,
                                                       const unsigned short* __restrict__ Wp,
                                                       const float* __restrict__ dinv,
                                                       unsigned char* __restrict__ out8,
                                                       int nrows) {
    __shared__ unsigned char f8s[64][128];
    int w = threadIdx.x >> 6;
    int l = threadIdx.x & 63;
    int m0 = blockIdx.x * 64 + w * 16;
    int kg = l >> 4;
    int cl = l & 15;
    int arow = m0 + cl;

    short8 a[4];
    if (arow < nrows) {
        const float4* Ar4 = (const float4*)(A + (size_t)arow * HH);
#pragma unroll
        for (int kb = 0; kb < 4; ++kb) {
            float4 u0 = Ar4[kb * 8 + kg * 2];
            float4 u1 = Ar4[kb * 8 + kg * 2 + 1];
            short8 tt;
            tt[0] = (short)f2bf(u0.x); tt[1] = (short)f2bf(u0.y);
            tt[2] = (short)f2bf(u0.z); tt[3] = (short)f2bf(u0.w);
            tt[4] = (short)f2bf(u1.x); tt[5] = (short)f2bf(u1.y);
            tt[6] = (short)f2bf(u1.z); tt[7] = (short)f2bf(u1.w);
            a[kb] = tt;
        }
    } else {
        short8 z = {};
#pragma unroll
        for (int kb = 0; kb < 4; ++kb) a[kb] = z;
    }

    float dv[4];
#pragma unroll
    for (int r = 0; r < 4; ++r) {
        int orow = m0 + kg * 4 + r;
        dv[r] = (orow < nrows) ? dinv[orow] : 0.f;
    }

#pragma unroll
    for (int cb = 0; cb < 8; ++cb) {
        f32x4 acc = {0.f, 0.f, 0.f, 0.f};
#pragma unroll
        for (int kb = 0; kb < 4; ++kb) {
            short8 b = *(const short8*)(Wp + (size_t)(cb * 4 + kb) * 512 + l * 8);
            acc = __builtin_amdgcn_mfma_f32_16x16x32_bf16(a[kb], b, acc, 0, 0, 0);
        }
#pragma unroll
        for (int r = 0; r < 4; ++r)
            f8s[w * 16 + kg * 4 + r][cb * 16 + cl] = f8enc1(acc[r] * dv[r]);
    }
    __syncthreads();
    int blk0 = blockIdx.x * 64;
    for (int u = threadIdx.x; u < 512; u += 256) {
        int row = u >> 3, c16 = u & 7;
        int grow = blk0 + row;
        if (grow < nrows)
            ((uint4*)out8)[(size_t)grow * 8 + c16] = ((const uint4*)&f8s[row][0])[c16];
    }
}

// ===== FUSED agg(layer l) + gemm(layer l+1): 32 nodes/block, no h8 round-trip =====
// Conflict-free LDS layout: row r's features f=16q+j stored as two 16B units at
// byte cols q*16 (j<8) and 128+q*16 (j>=8), swizzled ^((r&7)<<4).
__global__ __launch_bounds__(256) void agg_gemm_kernel(const unsigned char* __restrict__ t8in,
                                                       const int* __restrict__ offs,
                                                       const int* __restrict__ csrc,
                                                       const float* __restrict__ dinv,
                                                       const float* __restrict__ bias,
                                                       const unsigned short* __restrict__ Wp,
                                                       unsigned char* __restrict__ t8out) {
    __shared__ unsigned char hbuf[32 * 256];
    __shared__ unsigned char f8s[32][128];
    __shared__ float sdinv[32];
    int n0 = blockIdx.x * 32;
    int ln = threadIdx.x >> 3;                 // node slot 0..31
    int lane = threadIdx.x & 7;                // features lane*16..+15
    int n = n0 + ln;

    // ---- phase 1: aggregation ----
    int beg = offs[n], end = offs[n + 1];
    const uint4* g16 = (const uint4*)t8in;
    f32x2 acc2[8] = {};
    f32x2 d2[4];
    int e = beg;
    for (; e + 7 < end; e += 8) {
        uint4 v[8];
#pragma unroll
        for (int q = 0; q < 8; ++q)
            v[q] = g16[(size_t)csrc[e + q] * 8 + lane];
#pragma unroll
        for (int q = 0; q < 8; ++q) {
            uint2 a, b;
            a.x = v[q].x; a.y = v[q].y; b.x = v[q].z; b.y = v[q].w;
            dec8p(a, d2);
#pragma unroll
            for (int k = 0; k < 4; ++k) acc2[k] += d2[k];
            dec8p(b, d2);
#pragma unroll
            for (int k = 0; k < 4; ++k) acc2[k + 4] += d2[k];
        }
    }
    for (; e <= end; ++e) {                    // includes self term at e==end
        int s = (e < end) ? csrc[e] : n;
        uint4 v = g16[(size_t)s * 8 + lane];
        uint2 a, b;
        a.x = v.x; a.y = v.y; b.x = v.z; b.y = v.w;
        dec8p(a, d2);
#pragma unroll
        for (int k = 0; k < 4; ++k) acc2[k] += d2[k];
        dec8p(b, d2);
#pragma unroll
        for (int k = 0; k < 4; ++k) acc2[k + 4] += d2[k];
    }
    float dn = dinv[n];
    if (lane == 0) sdinv[ln] = dn;
    const float4* bv = (const float4*)(bias + lane * 16);
    float bb[16];
    {
        float4 b0 = bv[0], b1 = bv[1], b2 = bv[2], b3 = bv[3];
        bb[0]=b0.x; bb[1]=b0.y; bb[2]=b0.z; bb[3]=b0.w;
        bb[4]=b1.x; bb[5]=b1.y; bb[6]=b1.z; bb[7]=b1.w;
        bb[8]=b2.x; bb[9]=b2.y; bb[10]=b2.z; bb[11]=b2.w;
        bb[12]=b3.x; bb[13]=b3.y; bb[14]=b3.z; bb[15]=b3.w;
    }
    float o[16];
#pragma unroll
    for (int j = 0; j < 16; ++j)
        o[j] = fmaxf(fmaf(acc2[j >> 1][j & 1], dn, bb[j]), 0.f);
    uint4 u0, u1;
    u0.x = pack2bf(o[0], o[1]);  u0.y = pack2bf(o[2], o[3]);
    u0.z = pack2bf(o[4], o[5]);  u0.w = pack2bf(o[6], o[7]);
    u1.x = pack2bf(o[8], o[9]);  u1.y = pack2bf(o[10], o[11]);
    u1.z = pack2bf(o[12], o[13]); u1.w = pack2bf(o[14], o[15]);
    unsigned swz = (unsigned)((ln & 7) << 4);
    unsigned rowbase = (unsigned)ln * 256;
    *(uint4*)(hbuf + ((rowbase + (unsigned)lane * 16) ^ swz)) = u0;           // j<8 half
    *(uint4*)(hbuf + ((rowbase + 128u + (unsigned)lane * 16) ^ swz)) = u1;    // j>=8 half
    __syncthreads();

    // ---- phase 2: next-layer GEMM on the 32 rows ----
    int wv = threadIdx.x >> 6;
    int l = threadIdx.x & 63;
    int rt = wv & 1;
    int ch = wv >> 1;
    int kg = l >> 4;
    int cl = l & 15;
    int arow = rt * 16 + cl;
    unsigned rswz = (unsigned)((arow & 7) << 4);
    short8 a[4];
#pragma unroll
    for (int kb = 0; kb < 4; ++kb) {
        int m = kb * 4 + kg;                               // feature block 8m..8m+7
        unsigned col = (unsigned)((m & 1) * 128 + (m >> 1) * 16);
        unsigned boff = (unsigned)arow * 256 + col;
        a[kb] = *(const short8*)(hbuf + (boff ^ rswz));
    }
    float dv[4];
#pragma unroll
    for (int r = 0; r < 4; ++r) dv[r] = sdinv[rt * 16 + kg * 4 + r];
#pragma unroll
    for (int q = 0; q < 4; ++q) {
        int cb = ch * 4 + q;
        f32x4 acc = {0.f, 0.f, 0.f, 0.f};
#pragma unroll
        for (int kb = 0; kb < 4; ++kb) {
            short8 b = *(const short8*)(Wp + (size_t)(cb * 4 + kb) * 512 + l * 8);
            acc = __builtin_amdgcn_mfma_f32_16x16x32_bf16(a[kb], b, acc, 0, 0, 0);
        }
#pragma unroll
        for (int r = 0; r < 4; ++r)
            f8s[rt * 16 + kg * 4 + r][cb * 16 + cl] = f8enc1(acc[r] * dv[r]);
    }
    __syncthreads();
    int row2 = threadIdx.x >> 3, c16 = threadIdx.x & 7;
    ((uint4*)t8out)[(size_t)(n0 + row2) * 8 + c16] = ((const uint4*)&f8s[row2][0])[c16];
}

// ---- standalone aggregation (final layer -> h8 for pooling) ----
__global__ __launch_bounds__(256) void agg_relu_kernel(const unsigned char* __restrict__ t8,
                                                       const int* __restrict__ offs,
                                                       const int* __restrict__ csrc,
                                                       const float* __restrict__ dinv,
                                                       const float* __restrict__ bias,
                                                       unsigned char* __restrict__ hOut) {
    int n = blockIdx.x * 32 + (threadIdx.x >> 3);
    if (n >= NN) return;
    int lane = threadIdx.x & 7;
    int beg = offs[n], end = offs[n + 1];
    const uint4* g16 = (const uint4*)t8;
    f32x2 acc2[8] = {};
    f32x2 d2[4];
    int e = beg;
    for (; e + 7 < end; e += 8) {
        uint4 v[8];
#pragma unroll
        for (int q = 0; q < 8; ++q)
            v[q] = g16[(size_t)csrc[e + q] * 8 + lane];
#pragma unroll
        for (int q = 0; q < 8; ++q) {
            uint2 a, b;
            a.x = v[q].x; a.y = v[q].y; b.x = v[q].z; b.y = v[q].w;
            dec8p(a, d2);
#pragma unroll
            for (int k = 0; k < 4; ++k) acc2[k] += d2[k];
            dec8p(b, d2);
#pragma unroll
            for (int k = 0; k < 4; ++k) acc2[k + 4] += d2[k];
        }
    }
    for (; e <= end; ++e) {
        int s = (e < end) ? csrc[e] : n;
        uint4 v = g16[(size_t)s * 8 + lane];
        uint2 a, b;
        a.x = v.x; a.y = v.y; b.x = v.z; b.y = v.w;
        dec8p(a, d2);
#pragma unroll
        for (int k = 0; k < 4; ++k) acc2[k] += d2[k];
        dec8p(b, d2);
#pragma unroll
        for (int k = 0; k < 4; ++k) acc2[k + 4] += d2[k];
    }
    float dn = dinv[n];
    const float4* bv = (const float4*)(bias + lane * 16);
    float bb[16];
    float4 b0 = bv[0], b1 = bv[1], b2 = bv[2], b3 = bv[3];
    bb[0]=b0.x; bb[1]=b0.y; bb[2]=b0.z; bb[3]=b0.w;
    bb[4]=b1.x; bb[5]=b1.y; bb[6]=b1.z; bb[7]=b1.w;
    bb[8]=b2.x; bb[9]=b2.y; bb[10]=b2.z; bb[11]=b2.w;
    bb[12]=b3.x; bb[13]=b3.y; bb[14]=b3.z; bb[15]=b3.w;
    float o[16];
#pragma unroll
    for (int j = 0; j < 16; ++j)
        o[j] = fmaxf(fmaf(acc2[j >> 1][j & 1], dn, bb[j]), 0.f);
    uint4 w;
    w.x = enc_pk4(o[0], o[1], o[2], o[3]);
    w.y = enc_pk4(o[4], o[5], o[6], o[7]);
    w.z = enc_pk4(o[8], o[9], o[10], o[11]);
    w.w = enc_pk4(o[12], o[13], o[14], o[15]);
    ((uint4*)hOut)[(size_t)n * 8 + lane] = w;
}

// -------- pooling stage 1: 16 segments/graph, partials to psum_seg (no atomics) --------
__global__ __launch_bounds__(256) void poolseg_kernel(const unsigned char* __restrict__ h8,
                                                      const int* __restrict__ batch,
                                                      float* __restrict__ psum_seg) {
    int g = blockIdx.x >> 4;
    int seg = blockIdx.x & (PSEG - 1);
    int t = threadIdx.x;
    int lo = 0, hi = NN;
    while (lo < hi) { int m = (lo + hi) >> 1; if (batch[m] < g) lo = m + 1; else hi = m; }
    int lb = lo;
    lo = 0; hi = NN;
    while (lo < hi) { int m = (lo + hi) >> 1; if (batch[m] <= g) lo = m + 1; else hi = m; }
    int ub = lo;
    int len = ub - lb;
    int b0 = lb + (int)(((long long)len * seg) / PSEG);
    int b1 = lb + (int)(((long long)len * (seg + 1)) / PSEG);

    int fg = t & 15;
    int rg = t >> 4;
    const uint2* gp = (const uint2*)h8;
    f32x2 acc2[4] = {};
    f32x2 d2[4];
    for (int n = b0 + rg; n < b1; n += 16) {
        uint2 v = gp[(size_t)n * 16 + fg];
        dec8p(v, d2);
#pragma unroll
        for (int k = 0; k < 4; ++k) acc2[k] += d2[k];
    }
    __shared__ float red[256][8];
#pragma unroll
    for (int j = 0; j < 8; ++j) red[t][j] = acc2[j >> 1][j & 1];
    __syncthreads();
    for (int off = 8; off >= 1; off >>= 1) {
        if (rg < off) {
#pragma unroll
            for (int j = 0; j < 8; ++j) red[t][j] += red[t + off * 16][j];
        }
        __syncthreads();
    }
    if (t < 16) {
#pragma unroll
        for (int j = 0; j < 8; ++j)
            psum_seg[((size_t)g * PSEG + seg) * HH + t * 8 + j] = red[t][j];
    }
}

// -------- pooling stage 2 + MLP + log_softmax: one block per graph --------
__global__ __launch_bounds__(128) void mlp2_kernel(const float* __restrict__ psum_seg,
                                                   const int* __restrict__ batch,
                                                   const float* __restrict__ Wl1,
                                                   const float* __restrict__ bl1,
                                                   const float* __restrict__ Wl2,
                                                   const float* __restrict__ bl2,
                                                   float* __restrict__ out) {
    __shared__ float p[128], o1[128], lg[CC];
    int g = blockIdx.x, t = threadIdx.x;
    int lo = 0, hi = NN;
    while (lo < hi) { int m = (lo + hi) >> 1; if (batch[m] < g) lo = m + 1; else hi = m; }
    int lb = lo;
    lo = 0; hi = NN;
    while (lo < hi) { int m = (lo + hi) >> 1; if (batch[m] <= g) lo = m + 1; else hi = m; }
    int len = lo - lb;
    float a = 0.f;
#pragma unroll
    for (int s = 0; s < PSEG; ++s)
        a += psum_seg[((size_t)g * PSEG + s) * HH + t];
    p[t] = a / fmaxf((float)len, 1.f);
    __syncthreads();
    float acc = bl1[t];
    for (int k = 0; k < HH; ++k) acc = fmaf(p[k], Wl1[k * HH + t], acc);
    o1[t] = fmaxf(acc, 0.f);
    __syncthreads();
    if (t < CC) {
        float a2 = bl2[t];
        for (int j = 0; j < HH; ++j) a2 = fmaf(o1[j], Wl2[j * CC + t], a2);
        lg[t] = a2;
    }
    __syncthreads();
    if (t == 0) {
        float m = lg[0];
        for (int c = 1; c < CC; ++c) m = fmaxf(m, lg[c]);
        float s = 0.f;
        for (int c = 0; c < CC; ++c) s += expf(lg[c] - m);
        float ls = logf(s);
        for (int c = 0; c < CC; ++c) out[g * CC + c] = lg[c] - m - ls;
    }
}

extern "C" void kernel_launch(void* const* d_in, const int* in_sizes, int n_in,
                              void* d_out, int out_size, void* d_ws, size_t ws_size,
                              hipStream_t stream) {
    const float* x   = (const float*)d_in[0];
    const int*   ei  = (const int*)d_in[1];
    const int*   bat = (const int*)d_in[2];
    const float* W1  = (const float*)d_in[3];
    const float* b1  = (const float*)d_in[4];
    const float* Wr1 = (const float*)d_in[5];
    const float* br1 = (const float*)d_in[6];
    const float* W2  = (const float*)d_in[7];
    const float* b2  = (const float*)d_in[8];
    const float* Wr  = (const float*)d_in[9];
    const float* br  = (const float*)d_in[10];
    const float* Wl1 = (const float*)d_in[11];
    const float* bl1 = (const float*)d_in[12];
    const float* Wl2 = (const float*)d_in[13];
    const float* bl2 = (const float*)d_in[14];
    float* out = (float*)d_out;

    // workspace carve-up (256B aligned)
    char* base = (char*)d_ws;
    size_t off = 0;
    auto alloc = [&](size_t bytes) {
        void* p = base + off;
        off += (bytes + 255) & ~(size_t)255;
        return p;
    };
    unsigned char* t8a  = (unsigned char*)alloc((size_t)NN * HH);
    unsigned char* t8b  = (unsigned char*)alloc((size_t)NN * HH);
    unsigned char* h8   = (unsigned char*)alloc((size_t)NN * HH);
    unsigned* eb32 = (unsigned*)alloc((size_t)NE * 4);
    int*   cc     = (int*)alloc((size_t)NCHUNK * NBUCKET * 4);
    int*   csrc   = (int*)alloc((size_t)NE * 4);
    int*   offs   = (int*)alloc((size_t)(NN + 1) * 4);
    float* dinv   = (float*)alloc((size_t)NN * 4);
    int*   tot    = (int*)alloc(NBUCKET * 4);
    unsigned short* Wpack = (unsigned short*)alloc(3 * 16384 * 2);
    float* bc     = (float*)alloc(3 * HH * 4);
    float* psum_seg = (float*)alloc((size_t)GG * PSEG * HH * 4);
    (void)ws_size; (void)in_sizes; (void)n_in; (void)out_size;

    // weight combine
    combw_kernel<<<192, 256, 0, stream>>>(W1, b1, Wr1, br1, W2, b2, Wr, br, Wpack, bc);

    // deterministic partition: 4 kernels, no global atomics
    partA1_kernel<<<NCHUNK, 256, 0, stream>>>(ei, cc);
    partA2_kernel<<<NBUCKET, 256, 0, stream>>>(cc, tot);
    partA3_kernel<<<NCHUNK, 256, 0, stream>>>(ei, cc, tot, eb32);
    partB_kernel<<<NBUCKET, 256, 0, stream>>>(eb32, tot, offs, dinv, csrc);

    const int GEMM_BLOCKS = (NN + 63) / 64;
    const int FUSE_BLOCKS = NN / 32;   // 3125, exact
    // layer 0 GEMM (f32 x direct)
    gemm_f32_kernel<<<GEMM_BLOCKS, 256, 0, stream>>>(x, Wpack, dinv, t8a, NN);
    // fused agg(L0)+gemm(L1): t8a -> t8b
    agg_gemm_kernel<<<FUSE_BLOCKS, 256, 0, stream>>>(t8a, offs, csrc, dinv, bc,
                                                     Wpack + 16384, t8b);
    // fused agg(L1)+gemm(L2): t8b -> t8a
    agg_gemm_kernel<<<FUSE_BLOCKS, 256, 0, stream>>>(t8b, offs, csrc, dinv, bc + HH,
                                                     Wpack + 2 * 16384, t8a);
    // final aggregation -> h8 (fp8) for pooling
    agg_relu_kernel<<<FUSE_BLOCKS, 256, 0, stream>>>(t8a, offs, csrc, dinv, bc + 2 * HH, h8);

    // pooling (parallel segments, no atomics) + readout
    poolseg_kernel<<<GG * PSEG, 256, 0, stream>>>(h8, bat, psum_seg);
    mlp2_kernel<<<GG, 128, 0, stream>>>(psum_seg, bat, Wl1, bl1, Wl2, bl2, out);
}